// Round 1
// baseline (223.441 us; speedup 1.0000x reference)
//
#include <hip/hip_runtime.h>

// Problem constants
#define T_DIM   100
#define N_NODES 25
#define C_DIM   128
#define B_DIM   64
#define G_TOTAL 6400          // B*T
#define GNV     3200          // N_NODES * C_DIM (per-graph elements)
#define CNT_PER_T 204800.0f   // B * N * C

// ws float offsets
#define WS_A2   0             // 625 floats: A2 = Ahat^2, row-major [n][m]
#define WS_RS1  640           // 25 floats: rowsum(Ahat)
#define WS_BW   768           // 128 floats: W2^T b1
#define WS_SUM  1024          // 100 floats: per-t sum      (zeroed each call)
#define WS_SSQ  1152          // 100 floats: per-t sumsq
#define WS_W12T 2048          // 16384 bf16 (= 8192 floats): W12^T, [c][v]

typedef __attribute__((ext_vector_type(8))) short short8;
typedef __attribute__((ext_vector_type(4))) float f32x4;

__device__ __forceinline__ unsigned short f2bf(float f) {
  unsigned int u = __float_as_uint(f);
  u += 0x7FFFu + ((u >> 16) & 1u);   // RNE
  return (unsigned short)(u >> 16);
}

// ---------------------------------------------------------------------------
// Kernel 0: build normalized adjacency, A2 = A^2, rowsums, zero stats.
__global__ void k_prep(const int* __restrict__ edge, float* __restrict__ wsf) {
  __shared__ float sA[N_NODES][N_NODES];
  __shared__ float sdeg[N_NODES];
  __shared__ float sdis[N_NODES];
  const int tid = threadIdx.x;  // 256

  if (tid < N_NODES) sdeg[tid] = 0.f;
  for (int j = tid; j < N_NODES * N_NODES; j += 256) ((float*)sA)[j] = 0.f;
  __syncthreads();
  if (tid < 64) atomicAdd(&sdeg[edge[64 + tid]], 1.f);  // tgt occurrences
  __syncthreads();
  if (tid < N_NODES) sdis[tid] = rsqrtf(sdeg[tid] + 1.f);  // +1 self-loop
  __syncthreads();
  if (tid < 64) {
    int s = edge[tid], tg = edge[64 + tid];
    atomicAdd(&sA[tg][s], sdis[s] * sdis[tg]);
  }
  __syncthreads();
  if (tid < N_NODES) atomicAdd(&sA[tid][tid], sdis[tid] * sdis[tid]);  // self-loop
  __syncthreads();
  // A2 = A @ A
  for (int j = tid; j < N_NODES * N_NODES; j += 256) {
    int n = j / N_NODES, m = j - n * N_NODES;
    float acc = 0.f;
    for (int k = 0; k < N_NODES; k++) acc = fmaf(sA[n][k], sA[k][m], acc);
    wsf[WS_A2 + j] = acc;
  }
  if (tid < N_NODES) {
    float rs = 0.f;
    for (int m = 0; m < N_NODES; m++) rs += sA[tid][m];
    wsf[WS_RS1 + tid] = rs;
  }
  if (tid < T_DIM) { wsf[WS_SUM + tid] = 0.f; wsf[WS_SSQ + tid] = 0.f; }
}

// ---------------------------------------------------------------------------
// Kernel 0b: W12T[c][v] = sum_u W1[v][u]*W2[u][c]  (bf16), bw = W2^T b1.
__global__ void k_wprep(const float* __restrict__ W1, const float* __restrict__ W2,
                        const float* __restrict__ b1, float* __restrict__ wsf) {
  int j = blockIdx.x * 256 + threadIdx.x;  // 16384
  int c = j & 127, v = j >> 7;             // v wave-uniform -> W1 row via s_load
  float acc = 0.f;
#pragma unroll 8
  for (int u = 0; u < 128; u++) acc = fmaf(W1[v * 128 + u], W2[u * 128 + c], acc);
  ((unsigned short*)(wsf + WS_W12T))[c * 128 + v] = f2bf(acc);
  if (j < 128) {
    float a2 = 0.f;
    for (int u = 0; u < 128; u++) a2 = fmaf(W2[u * 128 + j], b1[u], a2);
    wsf[WS_BW + j] = a2;
  }
}

// ---------------------------------------------------------------------------
// Kernel 1: per block: 4 graphs (same t, b = bq*4..bq*4+3).
//   XA = A2 @ X_g  (VALU, bf16 into swizzled LDS)  -> h2 = XA @ W12 (MFMA)
//   h2 += rank-1 bias; store fp32 to out; accumulate per-t stats.
__global__ __launch_bounds__(256) void k_main(const float* __restrict__ x,
                                              const float* __restrict__ b2,
                                              const float* __restrict__ wsc,
                                              float* __restrict__ stats,
                                              float* __restrict__ out) {
  __shared__ __align__(16) unsigned short XA[112 * 128];  // A-operand, [row][k] swizzled
  __shared__ __align__(16) unsigned short WT[128 * 128];  // B-operand, [c][v] swizzled
  __shared__ float rs1[32];
  __shared__ float red[8];
  const int tid = threadIdx.x;
  const int bid = blockIdx.x;
  const int t = bid % T_DIM;
  const int bq = bid / T_DIM;

  // Stage W12T into LDS; XOR-swizzle 16B chunks by row&15 (bank-conflict fix).
  {
    const uint4* wg = (const uint4*)(wsc + WS_W12T);
    uint4* wl = (uint4*)WT;
    for (int j = tid; j < 2048; j += 256) {
      int row = j >> 4, cc = j & 15;
      wl[(row << 4) | (cc ^ (row & 15))] = wg[j];
    }
  }
  if (tid < N_NODES) rs1[tid] = wsc[WS_RS1 + tid];
  for (int j = tid; j < 12 * 128; j += 256)   // zero M-pad rows 100..111
    XA[(100 + (j >> 7)) * 128 + (j & 127)] = 0;

  // XA = A2 @ X: thread owns two (graph, v) columns. A2 reads are wave-uniform.
  {
    const int v = tid & 127;
    const int gl0 = tid >> 7;                       // 0..1 ; second col is gl0+2
    const float* A2 = wsc + WS_A2;
    const int g0 = (bq * 4 + gl0) * T_DIM + t;
    const float* xp0 = x + g0 * GNV + v;
    const float* xp1 = xp0 + 2 * T_DIM * GNV;
    float x0[25], x1[25];
#pragma unroll
    for (int m = 0; m < 25; m++) { x0[m] = xp0[m * 128]; x1[m] = xp1[m * 128]; }
    for (int n = 0; n < 25; n++) {
      float a0 = 0.f, a1 = 0.f;
#pragma unroll
      for (int m = 0; m < 25; m++) {
        float w = A2[n * 25 + m];
        a0 = fmaf(w, x0[m], a0);
        a1 = fmaf(w, x1[m], a1);
      }
      int r0 = gl0 * 25 + n, r1 = r0 + 50;
      XA[r0 * 128 + (v ^ ((r0 & 15) << 3))] = f2bf(a0);
      XA[r1 * 128 + (v ^ ((r1 & 15) << 3))] = f2bf(a1);
    }
  }
  __syncthreads();

  // MFMA: wave wv covers c in [wv*32, wv*32+32), full M=112. 56 MFMAs/wave.
  const int wv = tid >> 6, lane = tid & 63, quad = lane >> 4, l16 = lane & 15;
  f32x4 acc[7][2];
#pragma unroll
  for (int mt = 0; mt < 7; mt++)
#pragma unroll
    for (int nt = 0; nt < 2; nt++)
#pragma unroll
      for (int r = 0; r < 4; r++) acc[mt][nt][r] = 0.f;

#pragma unroll
  for (int ks = 0; ks < 4; ks++) {
    const int cc = (ks << 2) | quad;  // 16B chunk index along k
    short8 bfr[2];
#pragma unroll
    for (int nt = 0; nt < 2; nt++) {
      int brow = wv * 32 + nt * 16 + l16;
      bfr[nt] = *(const short8*)&WT[brow * 128 + ((cc ^ (brow & 15)) << 3)];
    }
#pragma unroll
    for (int mt = 0; mt < 7; mt++) {
      int arow = mt * 16 + l16;
      short8 afr = *(const short8*)&XA[arow * 128 + ((cc ^ (arow & 15)) << 3)];
#pragma unroll
      for (int nt = 0; nt < 2; nt++)
        acc[mt][nt] = __builtin_amdgcn_mfma_f32_16x16x32_bf16(afr, bfr[nt], acc[mt][nt], 0, 0, 0);
    }
  }

  // Epilogue: h2 = acc + rs1[n]*bw[c] + b2[c]; store + stats.
  const int c0i = wv * 32 + l16;
  const float bw0 = wsc[WS_BW + c0i], bw1 = wsc[WS_BW + c0i + 16];
  const float bb0 = b2[c0i], bb1 = b2[c0i + 16];
  float sum = 0.f, ssq = 0.f;
#pragma unroll
  for (int mt = 0; mt < 7; mt++) {
#pragma unroll
    for (int r = 0; r < 4; r++) {
      int row = mt * 16 + quad * 4 + r;
      if (row < 100) {
        int gl = row / 25;
        int n = row - gl * 25;
        float rsn = rs1[n];
        int g = (bq * 4 + gl) * T_DIM + t;
        int ob = g * GNV + n * 128 + c0i;
        float v0 = acc[mt][0][r] + rsn * bw0 + bb0;
        float v1 = acc[mt][1][r] + rsn * bw1 + bb1;
        out[ob] = v0;
        out[ob + 16] = v1;
        sum += v0 + v1;
        ssq += v0 * v0 + v1 * v1;
      }
    }
  }
#pragma unroll
  for (int off = 32; off > 0; off >>= 1) {
    sum += __shfl_down(sum, off, 64);
    ssq += __shfl_down(ssq, off, 64);
  }
  if (lane == 0) { red[wv] = sum; red[4 + wv] = ssq; }
  __syncthreads();
  if (tid == 0) {
    atomicAdd(&stats[t], red[0] + red[1] + red[2] + red[3]);
    atomicAdd(&stats[128 + t], red[4] + red[5] + red[6] + red[7]);
  }
}

// ---------------------------------------------------------------------------
// Kernel 2: in-place BatchNorm(T) + affine + ReLU over [B,T,N,C].
__global__ __launch_bounds__(256) void k_norm(float* __restrict__ out,
                                              const float* __restrict__ stats,
                                              const float* __restrict__ gamma,
                                              const float* __restrict__ beta) {
  int i4 = blockIdx.x * 256 + threadIdx.x;  // 5.12M float4s
  int base = i4 * 4;
  int t = (base / GNV) % T_DIM;             // all 4 elements share t (GNV%4==0)
  float s = stats[t], q = stats[128 + t];
  const float inv = 1.f / CNT_PER_T;
  float mean = s * inv;
  float var = fmaf(q, inv, -mean * mean);
  float rstd = rsqrtf(var + 1e-5f);
  float g = gamma[t] * rstd;
  float b = fmaf(-mean, g, beta[t]);
  float4 h = *(const float4*)(out + base);
  h.x = fmaxf(fmaf(h.x, g, b), 0.f);
  h.y = fmaxf(fmaf(h.y, g, b), 0.f);
  h.z = fmaxf(fmaf(h.z, g, b), 0.f);
  h.w = fmaxf(fmaf(h.w, g, b), 0.f);
  *(float4*)(out + base) = h;
}

// ---------------------------------------------------------------------------
extern "C" void kernel_launch(void* const* d_in, const int* in_sizes, int n_in,
                              void* d_out, int out_size, void* d_ws, size_t ws_size,
                              hipStream_t stream) {
  const float* x     = (const float*)d_in[0];
  const int*   edge  = (const int*)d_in[1];
  const float* W1    = (const float*)d_in[2];
  const float* b1    = (const float*)d_in[3];
  const float* W2    = (const float*)d_in[4];
  const float* b2    = (const float*)d_in[5];
  const float* gamma = (const float*)d_in[6];
  const float* beta  = (const float*)d_in[7];
  float* out = (float*)d_out;
  float* wsf = (float*)d_ws;

  k_prep<<<1, 256, 0, stream>>>(edge, wsf);
  k_wprep<<<64, 256, 0, stream>>>(W1, W2, b1, wsf);
  k_main<<<G_TOTAL / 4, 256, 0, stream>>>(x, b2, wsf, wsf + WS_SUM, out);
  k_norm<<<(B_DIM * T_DIM * GNV) / 4 / 256, 256, 0, stream>>>(out, wsf + WS_SUM, gamma, beta);
}

// Round 2
// 214.991 us; speedup vs baseline: 1.0393x; 1.0393x over previous
//
#include <hip/hip_runtime.h>

// Problem constants
#define T_DIM   100
#define N_NODES 25
#define C_DIM   128
#define B_DIM   64
#define G_TOTAL 6400          // B*T
#define GNV     3200          // N_NODES * C_DIM (per-graph elements)
#define CNT_PER_T 204800.0f   // B * N * C

// ws float offsets
#define WS_A2   0             // 625 floats: A2 = Ahat^2, row-major [n][m]
#define WS_RS1  640           // 25 floats: rowsum(Ahat)
#define WS_BW   768           // 128 floats: W2^T b1
#define WS_SUM  1024          // 100 floats: per-t sum      (zeroed each call)
#define WS_SSQ  1152          // 100 floats: per-t sumsq
#define WS_W12T 2048          // 16384 bf16 (= 8192 floats): W12^T, [c][v]

typedef __attribute__((ext_vector_type(8))) short short8;
typedef __attribute__((ext_vector_type(4))) float f32x4;

__device__ __forceinline__ unsigned short f2bf(float f) {
  unsigned int u = __float_as_uint(f);
  u += 0x7FFFu + ((u >> 16) & 1u);   // RNE
  return (unsigned short)(u >> 16);
}

// ---------------------------------------------------------------------------
// Kernel 0: build normalized adjacency, A2 = A^2, rowsums, zero stats.
__global__ void k_prep(const int* __restrict__ edge, float* __restrict__ wsf) {
  __shared__ float sA[N_NODES][N_NODES];
  __shared__ float sdeg[N_NODES];
  __shared__ float sdis[N_NODES];
  const int tid = threadIdx.x;  // 256

  if (tid < N_NODES) sdeg[tid] = 0.f;
  for (int j = tid; j < N_NODES * N_NODES; j += 256) ((float*)sA)[j] = 0.f;
  __syncthreads();
  if (tid < 64) atomicAdd(&sdeg[edge[64 + tid]], 1.f);  // tgt occurrences
  __syncthreads();
  if (tid < N_NODES) sdis[tid] = rsqrtf(sdeg[tid] + 1.f);  // +1 self-loop
  __syncthreads();
  if (tid < 64) {
    int s = edge[tid], tg = edge[64 + tid];
    atomicAdd(&sA[tg][s], sdis[s] * sdis[tg]);
  }
  __syncthreads();
  if (tid < N_NODES) atomicAdd(&sA[tid][tid], sdis[tid] * sdis[tid]);  // self-loop
  __syncthreads();
  // A2 = A @ A
  for (int j = tid; j < N_NODES * N_NODES; j += 256) {
    int n = j / N_NODES, m = j - n * N_NODES;
    float acc = 0.f;
    for (int k = 0; k < N_NODES; k++) acc = fmaf(sA[n][k], sA[k][m], acc);
    wsf[WS_A2 + j] = acc;
  }
  if (tid < N_NODES) {
    float rs = 0.f;
    for (int m = 0; m < N_NODES; m++) rs += sA[tid][m];
    wsf[WS_RS1 + tid] = rs;
  }
  if (tid < T_DIM) { wsf[WS_SUM + tid] = 0.f; wsf[WS_SSQ + tid] = 0.f; }
}

// ---------------------------------------------------------------------------
// Kernel 0b: W12T[c][v] = sum_u W1[v][u]*W2[u][c]  (bf16), bw = W2^T b1.
__global__ void k_wprep(const float* __restrict__ W1, const float* __restrict__ W2,
                        const float* __restrict__ b1, float* __restrict__ wsf) {
  int j = blockIdx.x * 256 + threadIdx.x;  // 16384
  int c = j & 127, v = j >> 7;             // v wave-uniform -> W1 row via s_load
  float acc = 0.f;
#pragma unroll 8
  for (int u = 0; u < 128; u++) acc = fmaf(W1[v * 128 + u], W2[u * 128 + c], acc);
  ((unsigned short*)(wsf + WS_W12T))[c * 128 + v] = f2bf(acc);
  if (j < 128) {
    float a2 = 0.f;
    for (int u = 0; u < 128; u++) a2 = fmaf(W2[u * 128 + j], b1[u], a2);
    wsf[WS_BW + j] = a2;
  }
}

// ---------------------------------------------------------------------------
// Kernel 1: per block: 4 graphs (same t, b = bq*4..bq*4+3).
//   XA = A2 @ X_g  (VALU, bf16 into swizzled LDS)  -> h2 = XA @ W12 (MFMA,
//   B-fragments held in registers straight from global — W12T is L2-hot).
//   h2 += rank-1 bias; store fp32 to out; accumulate per-t stats.
// __launch_bounds__(256,4): cap VGPR at 128 -> 4 waves/SIMD -> 4 blocks/CU
// (LDS is 28.8 KB -> not the limiter anymore).
__global__ __launch_bounds__(256, 4) void k_main(const float* __restrict__ x,
                                                 const float* __restrict__ b2,
                                                 const float* __restrict__ wsc,
                                                 float* __restrict__ stats,
                                                 float* __restrict__ out) {
  __shared__ __align__(16) unsigned short XA[112 * 128];  // A-operand, [row][k] swizzled
  __shared__ float rs1[32];
  __shared__ float red[8];
  const int tid = threadIdx.x;
  const int bid = blockIdx.x;
  const int t = bid % T_DIM;
  const int bq = bid / T_DIM;
  const int wv = tid >> 6, lane = tid & 63, quad = lane >> 4, l16 = lane & 15;

  if (tid < N_NODES) rs1[tid] = wsc[WS_RS1 + tid];
  for (int j = tid; j < 12 * 128; j += 256)   // zero M-pad rows 100..111
    XA[(100 + (j >> 7)) * 128 + (j & 127)] = 0;

  // XA = A2 @ X: thread owns two (graph, v) columns. A2 reads are wave-uniform.
  {
    const int v = tid & 127;
    const int gl0 = tid >> 7;                       // 0..1 ; second col is gl0+2
    const float* A2 = wsc + WS_A2;
    const int g0 = (bq * 4 + gl0) * T_DIM + t;
    const float* xp0 = x + g0 * GNV + v;
    const float* xp1 = xp0 + 2 * T_DIM * GNV;
    float x0[25], x1[25];
#pragma unroll
    for (int m = 0; m < 25; m++) { x0[m] = xp0[m * 128]; x1[m] = xp1[m * 128]; }
    for (int n = 0; n < 25; n++) {
      float a0 = 0.f, a1 = 0.f;
#pragma unroll
      for (int m = 0; m < 25; m++) {
        float w = A2[n * 25 + m];
        a0 = fmaf(w, x0[m], a0);
        a1 = fmaf(w, x1[m], a1);
      }
      int r0 = gl0 * 25 + n, r1 = r0 + 50;
      XA[r0 * 128 + (v ^ ((r0 & 15) << 3))] = f2bf(a0);
      XA[r1 * 128 + (v ^ ((r1 & 15) << 3))] = f2bf(a1);
    }
  }

  // B-fragment preload from global (register-pressure valley; latency hidden
  // by the barrier). Each lane: 2 rows x 4 chunks of 16B. 32 VGPRs.
  short8 bfr[2][4];
  {
    const unsigned short* Wg = (const unsigned short*)(wsc + WS_W12T);
#pragma unroll
    for (int nt = 0; nt < 2; nt++) {
      const short8* rp = (const short8*)&Wg[(wv * 32 + nt * 16 + l16) * 128];
#pragma unroll
      for (int ks = 0; ks < 4; ks++) bfr[nt][ks] = rp[(ks << 2) | quad];
    }
  }
  __syncthreads();

  // MFMA: wave wv covers c in [wv*32, wv*32+32), full M=112. 56 MFMAs/wave.
  f32x4 acc[7][2];
#pragma unroll
  for (int mt = 0; mt < 7; mt++)
#pragma unroll
    for (int nt = 0; nt < 2; nt++)
#pragma unroll
      for (int r = 0; r < 4; r++) acc[mt][nt][r] = 0.f;

#pragma unroll
  for (int ks = 0; ks < 4; ks++) {
    const int cc = (ks << 2) | quad;  // 16B chunk index along k
#pragma unroll
    for (int mt = 0; mt < 7; mt++) {
      int arow = mt * 16 + l16;
      short8 afr = *(const short8*)&XA[arow * 128 + ((cc ^ (arow & 15)) << 3)];
#pragma unroll
      for (int nt = 0; nt < 2; nt++)
        acc[mt][nt] = __builtin_amdgcn_mfma_f32_16x16x32_bf16(afr, bfr[nt][ks], acc[mt][nt], 0, 0, 0);
    }
  }

  // Epilogue: h2 = acc + rs1[n]*bw[c] + b2[c]; store + stats.
  const int c0i = wv * 32 + l16;
  const float bw0 = wsc[WS_BW + c0i], bw1 = wsc[WS_BW + c0i + 16];
  const float bb0 = b2[c0i], bb1 = b2[c0i + 16];
  float sum = 0.f, ssq = 0.f;
#pragma unroll
  for (int mt = 0; mt < 7; mt++) {
#pragma unroll
    for (int r = 0; r < 4; r++) {
      int row = mt * 16 + quad * 4 + r;
      if (row < 100) {
        int gl = row / 25;
        int n = row - gl * 25;
        float rsn = rs1[n];
        int g = (bq * 4 + gl) * T_DIM + t;
        int ob = g * GNV + n * 128 + c0i;
        float v0 = acc[mt][0][r] + rsn * bw0 + bb0;
        float v1 = acc[mt][1][r] + rsn * bw1 + bb1;
        out[ob] = v0;
        out[ob + 16] = v1;
        sum += v0 + v1;
        ssq += v0 * v0 + v1 * v1;
      }
    }
  }
#pragma unroll
  for (int off = 32; off > 0; off >>= 1) {
    sum += __shfl_down(sum, off, 64);
    ssq += __shfl_down(ssq, off, 64);
  }
  if (lane == 0) { red[wv] = sum; red[4 + wv] = ssq; }
  __syncthreads();
  if (tid == 0) {
    atomicAdd(&stats[t], red[0] + red[1] + red[2] + red[3]);
    atomicAdd(&stats[128 + t], red[4] + red[5] + red[6] + red[7]);
  }
}

// ---------------------------------------------------------------------------
// Kernel 2: in-place BatchNorm(T) + affine + ReLU over [B,T,N,C].
// 4 independent float4 RMWs per thread (MLP), grid-strided.
#define NORM_T4   5120000   // total float4s
#define NORM_STR  1280000   // stride between a thread's 4 float4s
__global__ __launch_bounds__(256) void k_norm(float* __restrict__ out,
                                              const float* __restrict__ stats,
                                              const float* __restrict__ gamma,
                                              const float* __restrict__ beta) {
  const int i0 = blockIdx.x * 256 + threadIdx.x;
  const float inv = 1.f / CNT_PER_T;
  float4 h[4];
  float g[4], bb[4];
  int base[4];
#pragma unroll
  for (int k = 0; k < 4; k++) {
    int i4 = i0 + k * NORM_STR;
    base[k] = i4 * 4;
    int t = (base[k] / GNV) % T_DIM;           // all 4 elems share t (GNV%4==0)
    float s = stats[t], q = stats[128 + t];
    float mean = s * inv;
    float var = fmaf(q, inv, -mean * mean);
    float rstd = rsqrtf(var + 1e-5f);
    g[k] = gamma[t] * rstd;
    bb[k] = fmaf(-mean, g[k], beta[t]);
    h[k] = *(const float4*)(out + base[k]);
  }
#pragma unroll
  for (int k = 0; k < 4; k++) {
    float4 v = h[k];
    v.x = fmaxf(fmaf(v.x, g[k], bb[k]), 0.f);
    v.y = fmaxf(fmaf(v.y, g[k], bb[k]), 0.f);
    v.z = fmaxf(fmaf(v.z, g[k], bb[k]), 0.f);
    v.w = fmaxf(fmaf(v.w, g[k], bb[k]), 0.f);
    *(float4*)(out + base[k]) = v;
  }
}

// ---------------------------------------------------------------------------
extern "C" void kernel_launch(void* const* d_in, const int* in_sizes, int n_in,
                              void* d_out, int out_size, void* d_ws, size_t ws_size,
                              hipStream_t stream) {
  const float* x     = (const float*)d_in[0];
  const int*   edge  = (const int*)d_in[1];
  const float* W1    = (const float*)d_in[2];
  const float* b1    = (const float*)d_in[3];
  const float* W2    = (const float*)d_in[4];
  const float* b2    = (const float*)d_in[5];
  const float* gamma = (const float*)d_in[6];
  const float* beta  = (const float*)d_in[7];
  float* out = (float*)d_out;
  float* wsf = (float*)d_ws;

  k_prep<<<1, 256, 0, stream>>>(edge, wsf);
  k_wprep<<<64, 256, 0, stream>>>(W1, W2, b1, wsf);
  k_main<<<G_TOTAL / 4, 256, 0, stream>>>(x, b2, wsf, wsf + WS_SUM, out);
  k_norm<<<NORM_STR / 256, 256, 0, stream>>>(out, wsf + WS_SUM, gamma, beta);
}

// Round 3
// 200.761 us; speedup vs baseline: 1.1130x; 1.0709x over previous
//
#include <hip/hip_runtime.h>

// Problem constants
#define T_DIM   100
#define N_NODES 25
#define C_DIM   128
#define B_DIM   64
#define G_TOTAL 6400          // B*T
#define GNV     3200          // N_NODES * C_DIM (per-graph elements)
#define CNT_PER_T 204800.0f   // B * N * C

// ws float offsets
#define WS_A2P  0             // 1024 bf16 (512 floats): A2 bf16, zero-padded 32x32 [m][k]
#define WS_RS1  640           // 25 floats: rowsum(Ahat)
#define WS_BW   768           // 128 floats: W2^T b1
#define WS_SUM  1024          // 100 floats: per-t sum   (zeroed each call)
#define WS_SSQ  1152          // 100 floats: per-t sumsq
#define WS_W12T 2048          // 16384 bf16 (= 8192 floats): W12^T, [c][v]

// Y_T layout in LDS: [g][c][row], row-stride 36 shorts (72 B: 18-dword stride,
// gcd(18,32)=2 -> 16-bank spread, 2-way free; 8B-aligned for b64 access).
#define YSTR  36
#define YGSTR (128 * YSTR)    // 4608 shorts per graph

typedef __attribute__((ext_vector_type(8))) short short8;
typedef __attribute__((ext_vector_type(4))) float f32x4;

__device__ __forceinline__ unsigned short f2bf(float f) {
  unsigned int u = __float_as_uint(f);
  u += 0x7FFFu + ((u >> 16) & 1u);   // RNE
  return (unsigned short)(u >> 16);
}
__device__ __forceinline__ unsigned int pack2bf(float a, float b) {
  return (unsigned int)f2bf(a) | ((unsigned int)f2bf(b) << 16);
}

// ---------------------------------------------------------------------------
// k_pre: blocks 0..63 = W12T/bw prep; block 64 = adjacency prep (independent).
__global__ void k_pre(const int* __restrict__ edge, const float* __restrict__ W1,
                      const float* __restrict__ W2, const float* __restrict__ b1,
                      float* __restrict__ wsf) {
  __shared__ float sA[N_NODES * N_NODES];
  __shared__ float sA2[N_NODES * N_NODES];
  __shared__ float sdeg[N_NODES];
  __shared__ float sdis[N_NODES];
  const int tid = threadIdx.x;  // 256

  if (blockIdx.x < 64) {
    // W12T[c][v] = sum_u W1[v][u]*W2[u][c]  (bf16), bw = W2^T b1.
    int j = blockIdx.x * 256 + tid;          // 16384
    int c = j & 127, v = j >> 7;             // v wave-uniform
    float acc = 0.f;
#pragma unroll 8
    for (int u = 0; u < 128; u++) acc = fmaf(W1[v * 128 + u], W2[u * 128 + c], acc);
    ((unsigned short*)(wsf + WS_W12T))[c * 128 + v] = f2bf(acc);
    if (j < 128) {
      float a2 = 0.f;
      for (int u = 0; u < 128; u++) a2 = fmaf(W2[u * 128 + j], b1[u], a2);
      wsf[WS_BW + j] = a2;
    }
    return;
  }

  // ---- block 64: normalized adjacency, A2 = Ahat^2 (bf16 padded), rowsums.
  if (tid < N_NODES) sdeg[tid] = 0.f;
  for (int j = tid; j < N_NODES * N_NODES; j += 256) sA[j] = 0.f;
  __syncthreads();
  if (tid < 64) atomicAdd(&sdeg[edge[64 + tid]], 1.f);  // tgt occurrences
  __syncthreads();
  if (tid < N_NODES) sdis[tid] = rsqrtf(sdeg[tid] + 1.f);  // +1 self-loop
  __syncthreads();
  if (tid < 64) {
    int s = edge[tid], tg = edge[64 + tid];
    atomicAdd(&sA[tg * N_NODES + s], sdis[s] * sdis[tg]);
  }
  __syncthreads();
  if (tid < N_NODES) atomicAdd(&sA[tid * N_NODES + tid], sdis[tid] * sdis[tid]);
  __syncthreads();
  for (int j = tid; j < N_NODES * N_NODES; j += 256) {
    int n = j / N_NODES, m = j - n * N_NODES;
    float acc = 0.f;
    for (int k = 0; k < N_NODES; k++) acc = fmaf(sA[n * N_NODES + k], sA[k * N_NODES + m], acc);
    sA2[j] = acc;
  }
  __syncthreads();
  // A2 bf16, zero-padded to 32x32 row-major [m][k]
  for (int j = tid; j < 1024; j += 256) {
    int m = j >> 5, k = j & 31;
    float v = (m < N_NODES && k < N_NODES) ? sA2[m * N_NODES + k] : 0.f;
    ((unsigned short*)(wsf + WS_A2P))[j] = f2bf(v);
  }
  if (tid < N_NODES) {
    float rs = 0.f;
    for (int m = 0; m < N_NODES; m++) rs += sA[tid * N_NODES + m];
    wsf[WS_RS1 + tid] = rs;
  }
  if (tid < T_DIM) { wsf[WS_SUM + tid] = 0.f; wsf[WS_SSQ + tid] = 0.f; }
}

// ---------------------------------------------------------------------------
// k_main: per block 4 graphs (same t, b = bq*4..+3), rows padded 28/graph.
//   Stage 1 (MFMA): Y = X_bf16 * W12            (X staged in LDS, swizzled)
//   Stage 2 (MFMA): H_g = A2_bf16 * Y_g         (Y_T in LDS, wave = graph)
//   Epilogue: H += rs1[n]*bw[c] + b2[c]; store fp32; per-t stats atomics.
__global__ __launch_bounds__(256, 4) void k_main(const float* __restrict__ x,
                                                 const float* __restrict__ b2,
                                                 const float* __restrict__ wsc,
                                                 float* __restrict__ stats,
                                                 float* __restrict__ out) {
  __shared__ __align__(16) unsigned short LB[4 * YGSTR];  // 36864 B union:
  //   phase A: X view, [row 0..111][k 0..127], XOR-swizzled, rows 28/graph
  //   phase B: Y_T view, [g][c][row] stride YSTR
  __shared__ float sBW[128];
  __shared__ float sB2[128];
  __shared__ float rs1[32];
  __shared__ float red[8];
  const int tid = threadIdx.x;
  const int bid = blockIdx.x;
  const int t = bid % T_DIM;
  const int bq = bid / T_DIM;
  const int wv = tid >> 6, lane = tid & 63, quad = lane >> 4, l16 = lane & 15;

  if (tid < 128) {
    sBW[tid] = wsc[WS_BW + tid];
    if (tid < N_NODES) rs1[tid] = wsc[WS_RS1 + tid];
  } else {
    sB2[tid - 128] = b2[tid - 128];
  }
  // zero X pad rows (3 per graph: g*28+25..27)
  for (int j = tid; j < 12 * 128; j += 256) {
    int pr = j >> 7;                       // 0..11
    int g = pr >> 2, rr = pr & 3;          // careful: 12 = 4g*3r -> use /3
    g = pr / 3; rr = pr - g * 3;
    LB[(g * 28 + 25 + rr) * 128 + (j & 127)] = 0;
  }

  // Load X (fp32), convert bf16, store to X view (swizzled by row&15).
  {
    const int v = tid & 127;
    const int gl0 = tid >> 7;                       // handles graphs gl0, gl0+2
    const int g0 = (bq * 4 + gl0) * T_DIM + t;
    const float* xp0 = x + g0 * GNV + v;
    const float* xp1 = xp0 + 2 * T_DIM * GNV;
    float x0[25], x1[25];
#pragma unroll
    for (int m = 0; m < 25; m++) { x0[m] = xp0[m * 128]; x1[m] = xp1[m * 128]; }
#pragma unroll
    for (int n = 0; n < 25; n++) {
      int r0 = gl0 * 28 + n, r1 = (gl0 + 2) * 28 + n;
      LB[r0 * 128 + (v ^ ((r0 & 15) << 3))] = f2bf(x0[n]);
      LB[r1 * 128 + (v ^ ((r1 & 15) << 3))] = f2bf(x1[n]);
    }
  }

  // W12T B-fragments straight from global (L2-hot), into regs.
  short8 bfr[2][4];
  {
    const unsigned short* Wg = (const unsigned short*)(wsc + WS_W12T);
#pragma unroll
    for (int nt = 0; nt < 2; nt++) {
      const short8* rp = (const short8*)&Wg[(wv * 32 + nt * 16 + l16) * 128];
#pragma unroll
      for (int ks = 0; ks < 4; ks++) bfr[nt][ks] = rp[(ks << 2) | quad];
    }
  }
  __syncthreads();

  // ---- Stage 1: Y = X * W12. Wave wv covers c in [wv*32, +32). 56 MFMA.
  f32x4 acc[7][2];
#pragma unroll
  for (int mt = 0; mt < 7; mt++)
#pragma unroll
    for (int nt = 0; nt < 2; nt++)
#pragma unroll
      for (int r = 0; r < 4; r++) acc[mt][nt][r] = 0.f;

#pragma unroll
  for (int ks = 0; ks < 4; ks++) {
    const int cc = (ks << 2) | quad;
#pragma unroll
    for (int mt = 0; mt < 7; mt++) {
      int arow = mt * 16 + l16;
      short8 afr = *(const short8*)&LB[arow * 128 + ((cc ^ (arow & 15)) << 3)];
#pragma unroll
      for (int nt = 0; nt < 2; nt++)
        acc[mt][nt] = __builtin_amdgcn_mfma_f32_16x16x32_bf16(afr, bfr[nt][ks], acc[mt][nt], 0, 0, 0);
    }
  }
  __syncthreads();  // all X reads done; LB becomes Y_T

  // Write Y -> Y_T (bf16). Each frag: 4 consecutive rows (one graph), col c.
#pragma unroll
  for (int mt = 0; mt < 7; mt++) {
    int row0 = mt * 16 + quad * 4;
    int g = row0 / 28;
    int rl = row0 - g * 28;                // multiple of 4 -> 8B aligned
#pragma unroll
    for (int nt = 0; nt < 2; nt++) {
      int c = wv * 32 + nt * 16 + l16;
      uint2 p;
      p.x = pack2bf(acc[mt][nt][0], acc[mt][nt][1]);
      p.y = pack2bf(acc[mt][nt][2], acc[mt][nt][3]);
      *(uint2*)&LB[g * YGSTR + c * YSTR + rl] = p;
    }
  }
  // zero Y_T pad rows 28..31 (A2p k-cols 25..31 are zero, but keep LDS clean)
  {
    uint2 z; z.x = 0u; z.y = 0u;
    for (int j = tid; j < 512; j += 256) {
      int g = j >> 7, c = j & 127;
      *(uint2*)&LB[g * YGSTR + c * YSTR + 28] = z;
    }
  }
  __syncthreads();

  // ---- Stage 2: H_g = A2 * Y_g. Wave wv <-> graph wv. 16 MFMA.
  const unsigned short* A2p = (const unsigned short*)(wsc + WS_A2P);
  short8 a2f[2];
#pragma unroll
  for (int mt2 = 0; mt2 < 2; mt2++)
    a2f[mt2] = *(const short8*)&A2p[(mt2 * 16 + l16) * 32 + quad * 8];

  const int obase = ((bq * 4 + wv) * T_DIM + t) * GNV;
  float sum = 0.f, ssq = 0.f;
#pragma unroll
  for (int half = 0; half < 2; half++) {
    f32x4 acc2[2][4];
#pragma unroll
    for (int mt2 = 0; mt2 < 2; mt2++)
#pragma unroll
      for (int nt = 0; nt < 4; nt++)
#pragma unroll
        for (int r = 0; r < 4; r++) acc2[mt2][nt][r] = 0.f;

#pragma unroll
    for (int nt = 0; nt < 4; nt++) {
      int c = (half * 4 + nt) * 16 + l16;
      int base = wv * YGSTR + c * YSTR + quad * 8;
      uint2 lo = *(const uint2*)&LB[base];
      uint2 hi = *(const uint2*)&LB[base + 4];
      uint4 w; w.x = lo.x; w.y = lo.y; w.z = hi.x; w.w = hi.y;
      short8 bf = __builtin_bit_cast(short8, w);
#pragma unroll
      for (int mt2 = 0; mt2 < 2; mt2++)
        acc2[mt2][nt] = __builtin_amdgcn_mfma_f32_16x16x32_bf16(a2f[mt2], bf, acc2[mt2][nt], 0, 0, 0);
    }
    // Epilogue for this half: bias + store + stats.
#pragma unroll
    for (int mt2 = 0; mt2 < 2; mt2++) {
#pragma unroll
      for (int nt = 0; nt < 4; nt++) {
        int c = (half * 4 + nt) * 16 + l16;
        float bw = sBW[c], bb = sB2[c];
#pragma unroll
        for (int r = 0; r < 4; r++) {
          int m = mt2 * 16 + quad * 4 + r;
          if (m < N_NODES) {
            float v = acc2[mt2][nt][r] + rs1[m] * bw + bb;
            out[obase + m * 128 + c] = v;
            sum += v;
            ssq += v * v;
          }
        }
      }
    }
  }

#pragma unroll
  for (int off = 32; off > 0; off >>= 1) {
    sum += __shfl_down(sum, off, 64);
    ssq += __shfl_down(ssq, off, 64);
  }
  if (lane == 0) { red[wv] = sum; red[4 + wv] = ssq; }
  __syncthreads();
  if (tid == 0) {
    atomicAdd(&stats[t], red[0] + red[1] + red[2] + red[3]);
    atomicAdd(&stats[128 + t], red[4] + red[5] + red[6] + red[7]);
  }
}

// ---------------------------------------------------------------------------
// k_norm: in-place BatchNorm(T) + affine + ReLU, 4 independent float4 RMWs.
#define NORM_STR  1280000   // float4 stride between a thread's 4 accesses
__global__ __launch_bounds__(256) void k_norm(float* __restrict__ out,
                                              const float* __restrict__ stats,
                                              const float* __restrict__ gamma,
                                              const float* __restrict__ beta) {
  const int i0 = blockIdx.x * 256 + threadIdx.x;
  const float inv = 1.f / CNT_PER_T;
  float4 h[4];
  float g[4], bb[4];
  int base[4];
#pragma unroll
  for (int k = 0; k < 4; k++) {
    int i4 = i0 + k * NORM_STR;
    base[k] = i4 * 4;
    int t = (base[k] / GNV) % T_DIM;           // all 4 elems share t (GNV%4==0)
    float s = stats[t], q = stats[128 + t];
    float mean = s * inv;
    float var = fmaf(q, inv, -mean * mean);
    float rstd = rsqrtf(var + 1e-5f);
    g[k] = gamma[t] * rstd;
    bb[k] = fmaf(-mean, g[k], beta[t]);
    h[k] = *(const float4*)(out + base[k]);
  }
#pragma unroll
  for (int k = 0; k < 4; k++) {
    float4 v = h[k];
    v.x = fmaxf(fmaf(v.x, g[k], bb[k]), 0.f);
    v.y = fmaxf(fmaf(v.y, g[k], bb[k]), 0.f);
    v.z = fmaxf(fmaf(v.z, g[k], bb[k]), 0.f);
    v.w = fmaxf(fmaf(v.w, g[k], bb[k]), 0.f);
    *(float4*)(out + base[k]) = v;
  }
}

// ---------------------------------------------------------------------------
extern "C" void kernel_launch(void* const* d_in, const int* in_sizes, int n_in,
                              void* d_out, int out_size, void* d_ws, size_t ws_size,
                              hipStream_t stream) {
  const float* x     = (const float*)d_in[0];
  const int*   edge  = (const int*)d_in[1];
  const float* W1    = (const float*)d_in[2];
  const float* b1    = (const float*)d_in[3];
  const float* W2    = (const float*)d_in[4];
  const float* b2    = (const float*)d_in[5];
  const float* gamma = (const float*)d_in[6];
  const float* beta  = (const float*)d_in[7];
  float* out = (float*)d_out;
  float* wsf = (float*)d_ws;

  k_pre<<<65, 256, 0, stream>>>(edge, W1, W2, b1, wsf);
  k_main<<<G_TOTAL / 4, 256, 0, stream>>>(x, b2, wsf, wsf + WS_SUM, out);
  k_norm<<<NORM_STR / 256, 256, 0, stream>>>(out, wsf + WS_SUM, gamma, beta);
}